// Round 1
// baseline (478.222 us; speedup 1.0000x reference)
//
#include <hip/hip_runtime.h>

#define N_NODES 500000
#define N_EDGES 8000000
#define N_GRAPHS 4096
#define IN_DIM 9
#define HID 64
#define TILE 128             // nodes per wave-private bucket (was 256)
#define TSR 12               // LDS tile row stride -> 48 B (f4,f4,scalar)
#define NKEYS 4096           // padded key space (used: 3907)
#define NKEYS_USED ((N_NODES + TILE - 1) / TILE)   // 3907
#define NSCAT 256            // hist/scatter chunks
#define CHUNK (N_EDGES / NSCAT)                    // 31250
#define HSB 1024             // hist/scatter block threads
#define RB 256               // reduce block threads (4 waves)
#define WPB 4
#define RGRID ((NKEYS_USED + 1) / 2)               // 1954 (2 buckets/block)
#define SCAN_N (NKEYS * NSCAT)                     // 1048576
#define SCAN_BLOCKS (SCAN_N / 1024)                // 1024
#define NW 8                 // src windows: src>>16
#define CAP 2560             // winsort LDS capacity (mean 2048, sd ~45 -> safe)

// ---------------- xpad: x[N][9] -> xa[N][8] (32B rows) + xb[N] --------------
__global__ void gin_xpad(const float* __restrict__ x,
                         float* __restrict__ xa, float* __restrict__ xb) {
    int i = blockIdx.x * blockDim.x + threadIdx.x;
    const int TOT = N_NODES * IN_DIM;
    if (i < TOT) {
        int n = i / IN_DIM, k = i - n * IN_DIM;
        float val = x[i];
        if (k < 8) xa[n * 8 + k] = val;
        else       xb[n] = val;
    }
}

// ---------------- precompute: v = w2@w3, c = b2.w3, out[g] = b3 -------------
__global__ void gin_precompute(const float* __restrict__ w2,
                               const float* __restrict__ b2,
                               const float* __restrict__ w3,
                               const float* __restrict__ b3,
                               float* __restrict__ out,
                               float* __restrict__ v,
                               float* __restrict__ c) {
    int g = blockIdx.x * blockDim.x + threadIdx.x;
    if (g < N_GRAPHS) out[g] = b3[0];
    if (blockIdx.x == 0) {
        int k = threadIdx.x;
        if (k < HID) {
            float acc = 0.f;
            #pragma unroll
            for (int j = 0; j < HID; ++j) acc += w2[k * HID + j] * w3[j];
            v[k] = acc;
        } else if (k == HID) {
            float acc = 0.f;
            #pragma unroll
            for (int j = 0; j < HID; ++j) acc += b2[j] * w3[j];
            *c = acc;
        }
    }
}

// ---------------- hist: cnt[key*NSCAT + s], key = dst>>7 --------------------
__global__ __launch_bounds__(HSB) void gin_hist(const int* __restrict__ ei,
                                                int* __restrict__ cnt) {
    __shared__ int h[NKEYS];              // 16 KB
    const int t = threadIdx.x, s = blockIdx.x;
    for (int b = t; b < NKEYS; b += HSB) h[b] = 0;
    __syncthreads();
    const int* dst = ei + N_EDGES;
    const int e0 = s * CHUNK, e1 = e0 + CHUNK;
    for (int e = e0 + t; e < e1; e += HSB)
        atomicAdd(&h[dst[e] >> 7], 1);
    __syncthreads();
    for (int b = t; b < NKEYS; b += HSB)
        cnt[b * NSCAT + s] = h[b];
}

// ---------------- parallel exclusive scan of cnt[SCAN_N] --------------------
__global__ __launch_bounds__(256) void gin_scan_a(int* __restrict__ cnt,
                                                  int* __restrict__ aux) {
    __shared__ int wtot[4];
    const int t = threadIdx.x, blk = blockIdx.x;
    int4* p = (int4*)(cnt + blk * 1024);
    int4 vv = p[t];
    int s0 = vv.x, s1 = s0 + vv.y, s2 = s1 + vv.z, s3 = s2 + vv.w;
    int lane = t & 63, w = t >> 6;
    int ws = s3;
    #pragma unroll
    for (int off = 1; off < 64; off <<= 1) {
        int o = __shfl_up(ws, off);
        if (lane >= off) ws += o;
    }
    if (lane == 63) wtot[w] = ws;
    __syncthreads();
    int wbase = 0;
    for (int i = 0; i < w; ++i) wbase += wtot[i];
    int excl = wbase + (ws - s3);
    int4 o4;
    o4.x = excl; o4.y = excl + s0; o4.z = excl + s1; o4.w = excl + s2;
    p[t] = o4;
    if (t == 255) aux[blk] = wbase + ws;
}

__global__ __launch_bounds__(64) void gin_scan_b(int* __restrict__ aux) {
    const int t = threadIdx.x;
    int4* p = (int4*)aux;
    int4 q0 = p[4 * t], q1 = p[4 * t + 1], q2 = p[4 * t + 2], q3 = p[4 * t + 3];
    int v[16] = {q0.x, q0.y, q0.z, q0.w, q1.x, q1.y, q1.z, q1.w,
                 q2.x, q2.y, q2.z, q2.w, q3.x, q3.y, q3.z, q3.w};
    int pre[16];
    int run = 0;
    #pragma unroll
    for (int i = 0; i < 16; ++i) { pre[i] = run; run += v[i]; }
    int ws = run;
    #pragma unroll
    for (int off = 1; off < 64; off <<= 1) {
        int o = __shfl_up(ws, off);
        if (t >= off) ws += o;
    }
    int excl = ws - run;
    #pragma unroll
    for (int i = 0; i < 16; ++i) v[i] = excl + pre[i];
    q0 = make_int4(v[0], v[1], v[2], v[3]);
    q1 = make_int4(v[4], v[5], v[6], v[7]);
    q2 = make_int4(v[8], v[9], v[10], v[11]);
    q3 = make_int4(v[12], v[13], v[14], v[15]);
    p[4 * t] = q0; p[4 * t + 1] = q1; p[4 * t + 2] = q2; p[4 * t + 3] = q3;
}

__global__ __launch_bounds__(256) void gin_scan_c(int* __restrict__ cnt,
                                                  const int* __restrict__ aux) {
    const int t = threadIdx.x, blk = blockIdx.x;
    int base = aux[blk];
    int4* p = (int4*)(cnt + blk * 1024);
    int4 vv = p[t];
    vv.x += base; vv.y += base; vv.z += base; vv.w += base;
    p[t] = vv;
}

// ---------------- scatter: fully LDS-staged, burst flush --------------------
__global__ __launch_bounds__(HSB) void gin_scatter(const int* __restrict__ ei,
                                                   const int* __restrict__ cnt,
                                                   unsigned int* __restrict__ packed) {
    __shared__ int cur[NKEYS];            // 16 KB
    __shared__ unsigned int E[CHUNK];     // 122.1 KB
    __shared__ int wtot[16];
    const int t = threadIdx.x, s = blockIdx.x;
    const int lane = t & 63, wave = t >> 6;

    // local exclusive scan of this block's per-key counts via flat-scan diffs
    const int kb = 4 * t;
    int c0, c1, c2, c3;
    {
        int f0 = (kb + 0) * NSCAT + s;
        int f1 = (kb + 1) * NSCAT + s;
        int f2 = (kb + 2) * NSCAT + s;
        int f3 = (kb + 3) * NSCAT + s;
        int a0 = cnt[f0], a1 = cnt[f1], a2 = cnt[f2], a3 = cnt[f3];
        c0 = cnt[f0 + 1] - a0;
        c1 = cnt[f1 + 1] - a1;
        c2 = cnt[f2 + 1] - a2;
        int n3 = (f3 + 1 < SCAN_N) ? cnt[f3 + 1] : N_EDGES;
        c3 = n3 - a3;
    }
    int sum4 = c0 + c1 + c2 + c3;
    int ws = sum4;
    #pragma unroll
    for (int off = 1; off < 64; off <<= 1) {
        int o = __shfl_up(ws, off);
        if (lane >= off) ws += o;
    }
    if (lane == 63) wtot[wave] = ws;
    __syncthreads();
    int wbase = 0;
    for (int i = 0; i < wave; ++i) wbase += wtot[i];
    int excl = wbase + ws - sum4;
    cur[kb + 0] = excl;
    cur[kb + 1] = excl + c0;
    cur[kb + 2] = excl + c0 + c1;
    cur[kb + 3] = excl + c0 + c1 + c2;
    __syncthreads();

    // phase 1: place edges into LDS at locally-sorted positions
    const int* src = ei;
    const int* dst = ei + N_EDGES;
    const int e0 = s * CHUNK, e1 = e0 + CHUNK;
    for (int e = e0 + t; e < e1; e += HSB) {
        int d = dst[e];
        int key = d >> 7;
        int lofs = atomicAdd(&cur[key], 1);
        E[lofs] = (unsigned int)src[e] | ((unsigned int)(d & (TILE - 1)) << 19);
    }
    __syncthreads();

    // phase 2: per-key burst flush with contiguous global stores
    const int KPW = NKEYS / 16;           // 256 keys per wave
    for (int k = wave * KPW; k < (wave + 1) * KPW; ++k) {
        int endl = cur[k];
        int startl = (k > 0) ? cur[k - 1] : 0;
        int m = endl - startl;
        if (m <= 0) continue;
        int gbase = cnt[k * NSCAT + s];
        for (int j = lane; j < m; j += 64)
            packed[gbase + j] = E[startl + j];
    }
}

// ---------------- winsort: reorder each bucket's edges by src window --------
__global__ __launch_bounds__(256) void gin_winsort(unsigned int* __restrict__ packed,
                                                   const int* __restrict__ cnt) {
    __shared__ unsigned int E[CAP];
    __shared__ unsigned int F[CAP];
    __shared__ int cw[NW * 256];
    __shared__ int winBase[NW];
    __shared__ int wt[NW];
    const int t = threadIdx.x, bucket = blockIdx.x;
    const int beg = cnt[bucket * NSCAT];
    const int end = cnt[(bucket + 1) * NSCAT];
    const int n = end - beg;
    if (n > CAP) return;                      // identity fallback (rare/never)

    for (int i = t; i < n; i += 256) E[i] = packed[beg + i];
    __syncthreads();

    int c[NW];
    #pragma unroll
    for (int w = 0; w < NW; ++w) c[w] = 0;
    for (int i = t; i < n; i += 256) { int w = (E[i] & 0x7FFFFu) >> 16; c[w]++; }
    #pragma unroll
    for (int w = 0; w < NW; ++w) cw[w * 256 + t] = c[w];
    __syncthreads();

    const int lane = t & 63, wv = t >> 6;
    for (int rep = 0; rep < 2; ++rep) {
        int w = wv + rep * 4;
        int carry = 0;
        #pragma unroll
        for (int chunkk = 0; chunkk < 4; ++chunkk) {
            int idx = chunkk * 64 + lane;
            int val = cw[w * 256 + idx];
            int sc = val;
            #pragma unroll
            for (int off = 1; off < 64; off <<= 1) {
                int o = __shfl_up(sc, off);
                if (lane >= off) sc += o;
            }
            cw[w * 256 + idx] = sc - val + carry;
            carry += __shfl(sc, 63);
        }
        if (lane == 0) wt[w] = carry;
    }
    __syncthreads();
    if (t == 0) {
        int run = 0;
        #pragma unroll
        for (int w = 0; w < NW; ++w) { winBase[w] = run; run += wt[w]; }
    }
    __syncthreads();

    int runc[NW];
    #pragma unroll
    for (int w = 0; w < NW; ++w) runc[w] = 0;
    for (int i = t; i < n; i += 256) {
        unsigned int pk = E[i];
        int w = (pk & 0x7FFFFu) >> 16;
        int pos = winBase[w] + cw[w * 256 + t] + runc[w]++;
        F[pos] = pk;
    }
    __syncthreads();
    for (int i = t; i < n; i += 256) packed[beg + i] = F[i];
}

// ---------------- reduce: 2 waves/bucket, wave-private tiles, merged --------
__global__ __launch_bounds__(RB) void gin_reduce(
    const unsigned int* __restrict__ packed,
    const int* __restrict__ cnt,
    const float* __restrict__ xa,
    const float* __restrict__ xb,
    const int* __restrict__ batch,
    const float* __restrict__ w1,
    const float* __restrict__ b1,
    const float* __restrict__ v,
    const float* __restrict__ c,
    float* __restrict__ out)
{
    __shared__ float tile[WPB * TILE * TSR];   // 24 KB: one 6 KB slice per wave
    __shared__ float w1s[IN_DIM * HID];
    __shared__ float b1s[HID];
    __shared__ float vs[HID];
    __shared__ float cs;

    const int t = threadIdx.x;
    const int wave = t >> 6, lane = t & 63;

    for (int i = t; i < WPB * TILE * TSR; i += RB) tile[i] = 0.f;
    for (int i = t; i < IN_DIM * HID; i += RB) w1s[i] = w1[i];
    if (t < HID) { b1s[t] = b1[t]; vs[t] = v[t]; }
    if (t == 0) cs = *c;
    __syncthreads();

    const int pair = wave >> 1;                 // which bucket in block
    const int half = wave & 1;                  // which edge half
    const int bucket = blockIdx.x * 2 + pair;
    float* tw = tile + wave * (TILE * TSR);     // wave-private slice

    const int beg = cnt[bucket * NSCAT];
    const int end = cnt[(bucket + 1) * NSCAT];  // padded keys hold N_EDGES
    const int n = end - beg;
    int mid = beg + (((n >> 1) + 63) & ~63);    // 64-aligned split keeps groups full
    if (mid > end) mid = end;
    const int e0 = half ? mid : beg;
    const int e1 = half ? end : mid;

    for (int p0 = e0; p0 < e1; p0 += 64) {
        int p = p0 + lane;
        bool valid = p < e1;
        unsigned int pk = valid ? packed[p] : 0u;
        int local = (int)(pk >> 19);             // 0..127
        int src = (int)(pk & 0x7FFFFu);
        const float4* xr = (const float4*)(xa + (size_t)src * 8);
        float4 a0 = xr[0], a1 = xr[1];
        float a2 = xb[src];

        // one-shot match mask + rank; conflict rounds cost 1 ballot each
        unsigned long long act0 = __ballot(valid);
        unsigned long long m = act0;
        #pragma unroll
        for (int bq = 0; bq < 7; ++bq) {
            unsigned long long bal = __ballot((local >> bq) & 1);
            m &= ((local >> bq) & 1) ? bal : ~bal;
        }
        unsigned long long mybit = 1ULL << lane;
        int rank = __popcll(m & (mybit - 1ULL));
        bool pending = valid;
        int r = 0;
        while (__any(pending)) {
            bool lead = pending && (rank == r);
            if (lead) {
                float4* row = (float4*)(tw + local * TSR);
                float4 r0 = row[0], r1 = row[1];
                float r2 = tw[local * TSR + 8];
                r0.x += a0.x; r0.y += a0.y; r0.z += a0.z; r0.w += a0.w;
                r1.x += a1.x; r1.y += a1.y; r1.z += a1.z; r1.w += a1.w;
                row[0] = r0; row[1] = r1;
                tw[local * TSR + 8] = r2 + a2;
                pending = false;
            }
            ++r;
        }
    }
    __syncthreads();

    // merge odd wave slice into even (per bucket), all 256 threads cooperate
    {
        float4* t4 = (float4*)tile;
        const int SL4 = TILE * TSR / 4;        // 384 float4 per slice
        for (int i = t; i < 2 * SL4; i += RB) {
            int pp = i / SL4, j = i - pp * SL4;
            float4 A = t4[(2 * pp) * SL4 + j];
            float4 B = t4[(2 * pp + 1) * SL4 + j];
            A.x += B.x; A.y += B.y; A.z += B.z; A.w += B.w;
            t4[(2 * pp) * SL4 + j] = A;
        }
    }
    __syncthreads();

    // fused MLP + scalar collapse + segmented pooled reduction
    const float* tb = tile + (2 * pair) * (TILE * TSR);
    const int nloc = half * 64 + lane;
    const int node = bucket * TILE + nloc;
    float s = 0.f;
    int b = -1;
    if (node < N_NODES) {
        const float4* xr = (const float4*)(xa + (size_t)node * 8);
        float4 q0 = xr[0], q1 = xr[1];
        float tv[IN_DIM];
        tv[0] = q0.x + tb[nloc * TSR + 0];
        tv[1] = q0.y + tb[nloc * TSR + 1];
        tv[2] = q0.z + tb[nloc * TSR + 2];
        tv[3] = q0.w + tb[nloc * TSR + 3];
        tv[4] = q1.x + tb[nloc * TSR + 4];
        tv[5] = q1.y + tb[nloc * TSR + 5];
        tv[6] = q1.z + tb[nloc * TSR + 6];
        tv[7] = q1.w + tb[nloc * TSR + 7];
        tv[8] = xb[node] + tb[nloc * TSR + 8];
        s = cs;
        #pragma unroll
        for (int j = 0; j < HID; ++j) {
            float z = b1s[j];
            #pragma unroll
            for (int k = 0; k < IN_DIM; ++k)
                z = fmaf(tv[k], w1s[k * HID + j], z);
            s += fmaxf(z, 0.f) * vs[j];
        }
        b = batch[node];
    }
    #pragma unroll
    for (int off = 1; off < 64; off <<= 1) {
        float so = __shfl_up(s, off);
        int bo = __shfl_up(b, off);
        if (lane >= off && bo == b) s += so;
    }
    int nb = __shfl_down(b, 1);
    bool tail = (lane == 63) || (nb != b);
    if (tail && b >= 0) atomicAdd(&out[b], s);
}

extern "C" void kernel_launch(void* const* d_in, const int* in_sizes, int n_in,
                              void* d_out, int out_size, void* d_ws, size_t ws_size,
                              hipStream_t stream) {
    const float* x     = (const float*)d_in[0];
    const int*   ei    = (const int*)d_in[1];
    const int*   batch = (const int*)d_in[2];
    const float* w1    = (const float*)d_in[3];
    const float* b1    = (const float*)d_in[4];
    const float* w2    = (const float*)d_in[5];
    const float* b2    = (const float*)d_in[6];
    const float* w3    = (const float*)d_in[7];
    const float* b3    = (const float*)d_in[8];
    float* out = (float*)d_out;

    // workspace (~54.2 MB)
    float* xa = (float*)d_ws;                                           // 16 MB
    float* xb = xa + (size_t)N_NODES * 8;                               // 2 MB
    unsigned int* packed = (unsigned int*)(xb + N_NODES);               // 32 MB
    int* cnt = (int*)(packed + N_EDGES);                                // 4 MB
    int* aux = cnt + SCAN_N;                                            // 4 KB
    float* v = (float*)(aux + SCAN_BLOCKS);                             // 64 floats
    float* c = v + HID;                                                 // 1 float

    gin_xpad<<<(N_NODES * IN_DIM + 255) / 256, 256, 0, stream>>>(x, xa, xb);
    gin_precompute<<<(N_GRAPHS + 255) / 256, 256, 0, stream>>>(w2, b2, w3, b3, out, v, c);
    gin_hist<<<NSCAT, HSB, 0, stream>>>(ei, cnt);
    gin_scan_a<<<SCAN_BLOCKS, 256, 0, stream>>>(cnt, aux);
    gin_scan_b<<<1, 64, 0, stream>>>(aux);
    gin_scan_c<<<SCAN_BLOCKS, 256, 0, stream>>>(cnt, aux);
    gin_scatter<<<NSCAT, HSB, 0, stream>>>(ei, cnt, packed);
    gin_winsort<<<NKEYS_USED, 256, 0, stream>>>(packed, cnt);
    gin_reduce<<<RGRID, RB, 0, stream>>>(packed, cnt, xa, xb, batch, w1, b1, v, c, out);
}

// Round 3
// 371.362 us; speedup vs baseline: 1.2878x; 1.2878x over previous
//
#include <hip/hip_runtime.h>

#define N_NODES 500000
#define N_EDGES 8000000
#define N_GRAPHS 4096
#define IN_DIM 9
#define HID 64
#define TILE 128             // nodes per wave-private bucket
#define TSR 12               // LDS tile row stride -> 48 B (f4,f4,scalar)
#define NKEYS 4096           // padded key space (used: 3907)
#define NKEYS_USED ((N_NODES + TILE - 1) / TILE)   // 3907
#define NSCAT 256            // hist/scatter chunks
#define CHUNK (N_EDGES / NSCAT)                    // 31250
#define HSB 1024             // hist/scatter block threads
#define RB 256               // reduce block threads (4 waves)
#define WPB 4
#define RGRID ((NKEYS_USED + 1) / 2)               // 1954 (2 buckets/block)
#define SCAN_N (NKEYS * NSCAT)                     // 1048576
#define SCAN_BLOCKS (SCAN_N / 1024)                // 1024
#define NW 8                 // src windows: src>>16
#define CAP 2560             // winsort LDS capacity (mean 2048, sd ~45 -> safe)

// ---------------- xpad: x[N][9] -> xa[N][8] (32B rows) + xb[N] --------------
__global__ void gin_xpad(const float* __restrict__ x,
                         float* __restrict__ xa, float* __restrict__ xb) {
    int i = blockIdx.x * blockDim.x + threadIdx.x;
    const int TOT = N_NODES * IN_DIM;
    if (i < TOT) {
        int n = i / IN_DIM, k = i - n * IN_DIM;
        float val = x[i];
        if (k < 8) xa[n * 8 + k] = val;
        else       xb[n] = val;
    }
}

// ---------------- precompute: v = w2@w3, c = b2.w3, out[g] = b3 -------------
__global__ void gin_precompute(const float* __restrict__ w2,
                               const float* __restrict__ b2,
                               const float* __restrict__ w3,
                               const float* __restrict__ b3,
                               float* __restrict__ out,
                               float* __restrict__ v,
                               float* __restrict__ c) {
    int g = blockIdx.x * blockDim.x + threadIdx.x;
    if (g < N_GRAPHS) out[g] = b3[0];
    if (blockIdx.x == 0) {
        int k = threadIdx.x;
        if (k < HID) {
            float acc = 0.f;
            #pragma unroll
            for (int j = 0; j < HID; ++j) acc += w2[k * HID + j] * w3[j];
            v[k] = acc;
        } else if (k == HID) {
            float acc = 0.f;
            #pragma unroll
            for (int j = 0; j < HID; ++j) acc += b2[j] * w3[j];
            *c = acc;
        }
    }
}

// ---------------- hist: cnt[key*NSCAT + s], key = dst>>7 --------------------
__global__ __launch_bounds__(HSB) void gin_hist(const int* __restrict__ ei,
                                                int* __restrict__ cnt) {
    __shared__ int h[NKEYS];              // 16 KB
    const int t = threadIdx.x, s = blockIdx.x;
    for (int b = t; b < NKEYS; b += HSB) h[b] = 0;
    __syncthreads();
    const int* dst = ei + N_EDGES;
    const int e0 = s * CHUNK, e1 = e0 + CHUNK;
    for (int e = e0 + t; e < e1; e += HSB)
        atomicAdd(&h[dst[e] >> 7], 1);
    __syncthreads();
    for (int b = t; b < NKEYS; b += HSB)
        cnt[b * NSCAT + s] = h[b];
}

// ---------------- parallel exclusive scan of cnt[SCAN_N] --------------------
__global__ __launch_bounds__(256) void gin_scan_a(int* __restrict__ cnt,
                                                  int* __restrict__ aux) {
    __shared__ int wtot[4];
    const int t = threadIdx.x, blk = blockIdx.x;
    int4* p = (int4*)(cnt + blk * 1024);
    int4 vv = p[t];
    int s0 = vv.x, s1 = s0 + vv.y, s2 = s1 + vv.z, s3 = s2 + vv.w;
    int lane = t & 63, w = t >> 6;
    int ws = s3;
    #pragma unroll
    for (int off = 1; off < 64; off <<= 1) {
        int o = __shfl_up(ws, off);
        if (lane >= off) ws += o;
    }
    if (lane == 63) wtot[w] = ws;
    __syncthreads();
    int wbase = 0;
    for (int i = 0; i < w; ++i) wbase += wtot[i];
    int excl = wbase + (ws - s3);
    int4 o4;
    o4.x = excl; o4.y = excl + s0; o4.z = excl + s1; o4.w = excl + s2;
    p[t] = o4;
    if (t == 255) aux[blk] = wbase + ws;
}

__global__ __launch_bounds__(64) void gin_scan_b(int* __restrict__ aux) {
    const int t = threadIdx.x;
    int4* p = (int4*)aux;
    int4 q0 = p[4 * t], q1 = p[4 * t + 1], q2 = p[4 * t + 2], q3 = p[4 * t + 3];
    int v[16] = {q0.x, q0.y, q0.z, q0.w, q1.x, q1.y, q1.z, q1.w,
                 q2.x, q2.y, q2.z, q2.w, q3.x, q3.y, q3.z, q3.w};
    int pre[16];
    int run = 0;
    #pragma unroll
    for (int i = 0; i < 16; ++i) { pre[i] = run; run += v[i]; }
    int ws = run;
    #pragma unroll
    for (int off = 1; off < 64; off <<= 1) {
        int o = __shfl_up(ws, off);
        if (t >= off) ws += o;
    }
    int excl = ws - run;
    #pragma unroll
    for (int i = 0; i < 16; ++i) v[i] = excl + pre[i];
    q0 = make_int4(v[0], v[1], v[2], v[3]);
    q1 = make_int4(v[4], v[5], v[6], v[7]);
    q2 = make_int4(v[8], v[9], v[10], v[11]);
    q3 = make_int4(v[12], v[13], v[14], v[15]);
    p[4 * t] = q0; p[4 * t + 1] = q1; p[4 * t + 2] = q2; p[4 * t + 3] = q3;
}

__global__ __launch_bounds__(256) void gin_scan_c(int* __restrict__ cnt,
                                                  const int* __restrict__ aux) {
    const int t = threadIdx.x, blk = blockIdx.x;
    int base = aux[blk];
    int4* p = (int4*)(cnt + blk * 1024);
    int4 vv = p[t];
    vv.x += base; vv.y += base; vv.z += base; vv.w += base;
    p[t] = vv;
}

// ---------------- scatter: LDS-staged, FLAT flush (binary-search key) -------
// Phase 1 places the whole chunk in LDS at locally-sorted positions.
// Phase 2: element i's global dest is dif[key]+i where dif[key] =
// gbase[key]-startl[key] (captured for free in the prologue). Each thread
// upper-bound-searches its element's key in cur[] (13 LDS steps: ceil(log2(
// NKEYS+1)) -- 12 leaves a length-1 ambiguous interval!) -> all 64 lanes
// active, zero global cnt loads, piecewise-contiguous wave stores.
__global__ __launch_bounds__(HSB) void gin_scatter(const int* __restrict__ ei,
                                                   const int* __restrict__ cnt,
                                                   unsigned int* __restrict__ packed) {
    __shared__ int cur[NKEYS];            // 16 KB (startl, then bumped to endl)
    __shared__ int dif[NKEYS];            // 16 KB (gbase - startl)
    __shared__ unsigned int E[CHUNK];     // 122.1 KB
    __shared__ int wtot[16];
    const int t = threadIdx.x, s = blockIdx.x;
    const int lane = t & 63, wave = t >> 6;

    // local exclusive scan of this block's per-key counts via flat-scan diffs
    const int kb = 4 * t;
    int a0, a1, a2, a3, c0, c1, c2, c3;
    {
        int f0 = (kb + 0) * NSCAT + s;
        int f1 = (kb + 1) * NSCAT + s;
        int f2 = (kb + 2) * NSCAT + s;
        int f3 = (kb + 3) * NSCAT + s;
        a0 = cnt[f0]; a1 = cnt[f1]; a2 = cnt[f2]; a3 = cnt[f3];
        c0 = cnt[f0 + 1] - a0;
        c1 = cnt[f1 + 1] - a1;
        c2 = cnt[f2 + 1] - a2;
        int n3 = (f3 + 1 < SCAN_N) ? cnt[f3 + 1] : N_EDGES;
        c3 = n3 - a3;
    }
    int sum4 = c0 + c1 + c2 + c3;
    int ws = sum4;
    #pragma unroll
    for (int off = 1; off < 64; off <<= 1) {
        int o = __shfl_up(ws, off);
        if (lane >= off) ws += o;
    }
    if (lane == 63) wtot[wave] = ws;
    __syncthreads();
    int wbase = 0;
    for (int i = 0; i < wave; ++i) wbase += wtot[i];
    int excl = wbase + ws - sum4;
    int s0 = excl, s1 = excl + c0, s2 = excl + c0 + c1, s3 = excl + c0 + c1 + c2;
    cur[kb + 0] = s0;  dif[kb + 0] = a0 - s0;
    cur[kb + 1] = s1;  dif[kb + 1] = a1 - s1;
    cur[kb + 2] = s2;  dif[kb + 2] = a2 - s2;
    cur[kb + 3] = s3;  dif[kb + 3] = a3 - s3;
    __syncthreads();

    // phase 1: place edges into LDS at locally-sorted positions
    const int* src = ei;
    const int* dst = ei + N_EDGES;
    const int e0 = s * CHUNK, e1 = e0 + CHUNK;
    for (int e = e0 + t; e < e1; e += HSB) {
        int d = dst[e];
        int key = d >> 7;
        int lofs = atomicAdd(&cur[key], 1);
        E[lofs] = (unsigned int)src[e] | ((unsigned int)(d & (TILE - 1)) << 19);
    }
    __syncthreads();
    // post-phase1: cur[k] = local END of key k's run (monotone, cur[last]=CHUNK)

    // phase 2: flat flush, one store per element, all lanes active
    for (int i = t; i < CHUNK; i += HSB) {
        unsigned int e = E[i];
        int lo = 0, hi = NKEYS;
        #pragma unroll
        for (int it = 0; it < 13; ++it) {      // ceil(log2(NKEYS+1)) = 13
            int mid = (lo + hi) >> 1;
            if (cur[mid] > i) hi = mid; else lo = mid + 1;
        }
        packed[dif[lo] + i] = e;
    }
}

// ---------------- winsort: reorder each bucket's edges by src window --------
__global__ __launch_bounds__(256) void gin_winsort(unsigned int* __restrict__ packed,
                                                   const int* __restrict__ cnt) {
    __shared__ unsigned int E[CAP];
    __shared__ unsigned int F[CAP];
    __shared__ int cw[NW * 256];
    __shared__ int winBase[NW];
    __shared__ int wt[NW];
    const int t = threadIdx.x, bucket = blockIdx.x;
    const int beg = cnt[bucket * NSCAT];
    const int end = cnt[(bucket + 1) * NSCAT];
    const int n = end - beg;
    if (n > CAP) return;                      // identity fallback (rare/never)

    for (int i = t; i < n; i += 256) E[i] = packed[beg + i];
    __syncthreads();

    int c[NW];
    #pragma unroll
    for (int w = 0; w < NW; ++w) c[w] = 0;
    for (int i = t; i < n; i += 256) { int w = (E[i] & 0x7FFFFu) >> 16; c[w]++; }
    #pragma unroll
    for (int w = 0; w < NW; ++w) cw[w * 256 + t] = c[w];
    __syncthreads();

    const int lane = t & 63, wv = t >> 6;
    for (int rep = 0; rep < 2; ++rep) {
        int w = wv + rep * 4;
        int carry = 0;
        #pragma unroll
        for (int chunkk = 0; chunkk < 4; ++chunkk) {
            int idx = chunkk * 64 + lane;
            int val = cw[w * 256 + idx];
            int sc = val;
            #pragma unroll
            for (int off = 1; off < 64; off <<= 1) {
                int o = __shfl_up(sc, off);
                if (lane >= off) sc += o;
            }
            cw[w * 256 + idx] = sc - val + carry;
            carry += __shfl(sc, 63);
        }
        if (lane == 0) wt[w] = carry;
    }
    __syncthreads();
    if (t == 0) {
        int run = 0;
        #pragma unroll
        for (int w = 0; w < NW; ++w) { winBase[w] = run; run += wt[w]; }
    }
    __syncthreads();

    int runc[NW];
    #pragma unroll
    for (int w = 0; w < NW; ++w) runc[w] = 0;
    for (int i = t; i < n; i += 256) {
        unsigned int pk = E[i];
        int w = (pk & 0x7FFFFu) >> 16;
        int pos = winBase[w] + cw[w * 256 + t] + runc[w]++;
        F[pos] = pk;
    }
    __syncthreads();
    for (int i = t; i < n; i += 256) packed[beg + i] = F[i];
}

// ---------------- reduce: 2 waves/bucket, wave-private tiles, merged --------
__global__ __launch_bounds__(RB) void gin_reduce(
    const unsigned int* __restrict__ packed,
    const int* __restrict__ cnt,
    const float* __restrict__ xa,
    const float* __restrict__ xb,
    const int* __restrict__ batch,
    const float* __restrict__ w1,
    const float* __restrict__ b1,
    const float* __restrict__ v,
    const float* __restrict__ c,
    float* __restrict__ out)
{
    __shared__ float tile[WPB * TILE * TSR];   // 24 KB: one 6 KB slice per wave
    __shared__ float w1s[IN_DIM * HID];
    __shared__ float b1s[HID];
    __shared__ float vs[HID];
    __shared__ float cs;

    const int t = threadIdx.x;
    const int wave = t >> 6, lane = t & 63;

    for (int i = t; i < WPB * TILE * TSR; i += RB) tile[i] = 0.f;
    for (int i = t; i < IN_DIM * HID; i += RB) w1s[i] = w1[i];
    if (t < HID) { b1s[t] = b1[t]; vs[t] = v[t]; }
    if (t == 0) cs = *c;
    __syncthreads();

    const int pair = wave >> 1;                 // which bucket in block
    const int half = wave & 1;                  // which edge half
    const int bucket = blockIdx.x * 2 + pair;
    float* tw = tile + wave * (TILE * TSR);     // wave-private slice

    const int beg = cnt[bucket * NSCAT];
    const int end = cnt[(bucket + 1) * NSCAT];  // padded keys hold N_EDGES
    const int n = end - beg;
    int mid = beg + (((n >> 1) + 63) & ~63);    // 64-aligned split keeps groups full
    if (mid > end) mid = end;
    const int e0 = half ? mid : beg;
    const int e1 = half ? end : mid;

    for (int p0 = e0; p0 < e1; p0 += 64) {
        int p = p0 + lane;
        bool valid = p < e1;
        unsigned int pk = valid ? packed[p] : 0u;
        int local = (int)(pk >> 19);             // 0..127
        int src = (int)(pk & 0x7FFFFu);
        const float4* xr = (const float4*)(xa + (size_t)src * 8);
        float4 a0 = xr[0], a1 = xr[1];
        float a2 = xb[src];

        // one-shot match mask + rank; conflict rounds cost 1 ballot each
        unsigned long long act0 = __ballot(valid);
        unsigned long long m = act0;
        #pragma unroll
        for (int bq = 0; bq < 7; ++bq) {
            unsigned long long bal = __ballot((local >> bq) & 1);
            m &= ((local >> bq) & 1) ? bal : ~bal;
        }
        unsigned long long mybit = 1ULL << lane;
        int rank = __popcll(m & (mybit - 1ULL));
        bool pending = valid;
        int r = 0;
        while (__any(pending)) {
            bool lead = pending && (rank == r);
            if (lead) {
                float4* row = (float4*)(tw + local * TSR);
                float4 r0 = row[0], r1 = row[1];
                float r2 = tw[local * TSR + 8];
                r0.x += a0.x; r0.y += a0.y; r0.z += a0.z; r0.w += a0.w;
                r1.x += a1.x; r1.y += a1.y; r1.z += a1.z; r1.w += a1.w;
                row[0] = r0; row[1] = r1;
                tw[local * TSR + 8] = r2 + a2;
                pending = false;
            }
            ++r;
        }
    }
    __syncthreads();

    // merge odd wave slice into even (per bucket), all 256 threads cooperate
    {
        float4* t4 = (float4*)tile;
        const int SL4 = TILE * TSR / 4;        // 384 float4 per slice
        for (int i = t; i < 2 * SL4; i += RB) {
            int pp = i / SL4, j = i - pp * SL4;
            float4 A = t4[(2 * pp) * SL4 + j];
            float4 B = t4[(2 * pp + 1) * SL4 + j];
            A.x += B.x; A.y += B.y; A.z += B.z; A.w += B.w;
            t4[(2 * pp) * SL4 + j] = A;
        }
    }
    __syncthreads();

    // fused MLP + scalar collapse + segmented pooled reduction
    const float* tb = tile + (2 * pair) * (TILE * TSR);
    const int nloc = half * 64 + lane;
    const int node = bucket * TILE + nloc;
    float s = 0.f;
    int b = -1;
    if (node < N_NODES) {
        const float4* xr = (const float4*)(xa + (size_t)node * 8);
        float4 q0 = xr[0], q1 = xr[1];
        float tv[IN_DIM];
        tv[0] = q0.x + tb[nloc * TSR + 0];
        tv[1] = q0.y + tb[nloc * TSR + 1];
        tv[2] = q0.z + tb[nloc * TSR + 2];
        tv[3] = q0.w + tb[nloc * TSR + 3];
        tv[4] = q1.x + tb[nloc * TSR + 4];
        tv[5] = q1.y + tb[nloc * TSR + 5];
        tv[6] = q1.z + tb[nloc * TSR + 6];
        tv[7] = q1.w + tb[nloc * TSR + 7];
        tv[8] = xb[node] + tb[nloc * TSR + 8];
        s = cs;
        #pragma unroll
        for (int j = 0; j < HID; ++j) {
            float z = b1s[j];
            #pragma unroll
            for (int k = 0; k < IN_DIM; ++k)
                z = fmaf(tv[k], w1s[k * HID + j], z);
            s += fmaxf(z, 0.f) * vs[j];
        }
        b = batch[node];
    }
    #pragma unroll
    for (int off = 1; off < 64; off <<= 1) {
        float so = __shfl_up(s, off);
        int bo = __shfl_up(b, off);
        if (lane >= off && bo == b) s += so;
    }
    int nb = __shfl_down(b, 1);
    bool tail = (lane == 63) || (nb != b);
    if (tail && b >= 0) atomicAdd(&out[b], s);
}

extern "C" void kernel_launch(void* const* d_in, const int* in_sizes, int n_in,
                              void* d_out, int out_size, void* d_ws, size_t ws_size,
                              hipStream_t stream) {
    const float* x     = (const float*)d_in[0];
    const int*   ei    = (const int*)d_in[1];
    const int*   batch = (const int*)d_in[2];
    const float* w1    = (const float*)d_in[3];
    const float* b1    = (const float*)d_in[4];
    const float* w2    = (const float*)d_in[5];
    const float* b2    = (const float*)d_in[6];
    const float* w3    = (const float*)d_in[7];
    const float* b3    = (const float*)d_in[8];
    float* out = (float*)d_out;

    // workspace (~54.2 MB)
    float* xa = (float*)d_ws;                                           // 16 MB
    float* xb = xa + (size_t)N_NODES * 8;                               // 2 MB
    unsigned int* packed = (unsigned int*)(xb + N_NODES);               // 32 MB
    int* cnt = (int*)(packed + N_EDGES);                                // 4 MB
    int* aux = cnt + SCAN_N;                                            // 4 KB
    float* v = (float*)(aux + SCAN_BLOCKS);                             // 64 floats
    float* c = v + HID;                                                 // 1 float

    gin_xpad<<<(N_NODES * IN_DIM + 255) / 256, 256, 0, stream>>>(x, xa, xb);
    gin_precompute<<<(N_GRAPHS + 255) / 256, 256, 0, stream>>>(w2, b2, w3, b3, out, v, c);
    gin_hist<<<NSCAT, HSB, 0, stream>>>(ei, cnt);
    gin_scan_a<<<SCAN_BLOCKS, 256, 0, stream>>>(cnt, aux);
    gin_scan_b<<<1, 64, 0, stream>>>(aux);
    gin_scan_c<<<SCAN_BLOCKS, 256, 0, stream>>>(cnt, aux);
    gin_scatter<<<NSCAT, HSB, 0, stream>>>(ei, cnt, packed);
    gin_winsort<<<NKEYS_USED, 256, 0, stream>>>(packed, cnt);
    gin_reduce<<<RGRID, RB, 0, stream>>>(packed, cnt, xa, xb, batch, w1, b1, v, c, out);
}

// Round 4
// 367.072 us; speedup vs baseline: 1.3028x; 1.0117x over previous
//
#include <hip/hip_runtime.h>

#define N_NODES 500000
#define N_EDGES 8000000
#define N_GRAPHS 4096
#define IN_DIM 9
#define HID 64
#define TILE 128             // nodes per wave-private bucket
#define TSR 12               // LDS tile row stride -> 48 B (f4,f4,scalar)
#define NKEYS 4096           // padded key space (used: 3907)
#define NKEYS_USED ((N_NODES + TILE - 1) / TILE)   // 3907
#define NSCAT 256            // hist/scatter chunks
#define CHUNK (N_EDGES / NSCAT)                    // 31250
#define HSB 1024             // hist/scatter block threads
#define RB 256               // reduce block threads (4 waves)
#define WPB 4
#define RGRID ((NKEYS_USED + 1) / 2)               // 1954 (2 buckets/block)
#define SCAN_N (NKEYS * NSCAT)                     // 1048576
#define SCAN_BLOCKS (SCAN_N / 1024)                // 1024
#define NW 8                 // src windows: src>>16
#define CAP 2560             // winsort LDS capacity (mean 2048, sd ~45 -> safe)

// ---------------- xpad: x[N][9] -> xa[N][8] (32B rows) + xb[N] --------------
__global__ void gin_xpad(const float* __restrict__ x,
                         float* __restrict__ xa, float* __restrict__ xb) {
    int i = blockIdx.x * blockDim.x + threadIdx.x;
    const int TOT = N_NODES * IN_DIM;
    if (i < TOT) {
        int n = i / IN_DIM, k = i - n * IN_DIM;
        float val = x[i];
        if (k < 8) xa[n * 8 + k] = val;
        else       xb[n] = val;
    }
}

// ---------------- precompute: v = w2@w3, c = b2.w3, out[g] = b3 -------------
__global__ void gin_precompute(const float* __restrict__ w2,
                               const float* __restrict__ b2,
                               const float* __restrict__ w3,
                               const float* __restrict__ b3,
                               float* __restrict__ out,
                               float* __restrict__ v,
                               float* __restrict__ c) {
    int g = blockIdx.x * blockDim.x + threadIdx.x;
    if (g < N_GRAPHS) out[g] = b3[0];
    if (blockIdx.x == 0) {
        int k = threadIdx.x;
        if (k < HID) {
            float acc = 0.f;
            #pragma unroll
            for (int j = 0; j < HID; ++j) acc += w2[k * HID + j] * w3[j];
            v[k] = acc;
        } else if (k == HID) {
            float acc = 0.f;
            #pragma unroll
            for (int j = 0; j < HID; ++j) acc += b2[j] * w3[j];
            *c = acc;
        }
    }
}

// ---------------- hist: cnt[key*NSCAT + s], key = dst>>7 --------------------
__global__ __launch_bounds__(HSB) void gin_hist(const int* __restrict__ ei,
                                                int* __restrict__ cnt) {
    __shared__ int h[NKEYS];              // 16 KB
    const int t = threadIdx.x, s = blockIdx.x;
    for (int b = t; b < NKEYS; b += HSB) h[b] = 0;
    __syncthreads();
    const int* dst = ei + N_EDGES;
    const int e0 = s * CHUNK, e1 = e0 + CHUNK;
    for (int e = e0 + t; e < e1; e += HSB)
        atomicAdd(&h[dst[e] >> 7], 1);
    __syncthreads();
    for (int b = t; b < NKEYS; b += HSB)
        cnt[b * NSCAT + s] = h[b];
}

// ---------------- parallel exclusive scan of cnt[SCAN_N] --------------------
__global__ __launch_bounds__(256) void gin_scan_a(int* __restrict__ cnt,
                                                  int* __restrict__ aux) {
    __shared__ int wtot[4];
    const int t = threadIdx.x, blk = blockIdx.x;
    int4* p = (int4*)(cnt + blk * 1024);
    int4 vv = p[t];
    int s0 = vv.x, s1 = s0 + vv.y, s2 = s1 + vv.z, s3 = s2 + vv.w;
    int lane = t & 63, w = t >> 6;
    int ws = s3;
    #pragma unroll
    for (int off = 1; off < 64; off <<= 1) {
        int o = __shfl_up(ws, off);
        if (lane >= off) ws += o;
    }
    if (lane == 63) wtot[w] = ws;
    __syncthreads();
    int wbase = 0;
    for (int i = 0; i < w; ++i) wbase += wtot[i];
    int excl = wbase + (ws - s3);
    int4 o4;
    o4.x = excl; o4.y = excl + s0; o4.z = excl + s1; o4.w = excl + s2;
    p[t] = o4;
    if (t == 255) aux[blk] = wbase + ws;
}

__global__ __launch_bounds__(64) void gin_scan_b(int* __restrict__ aux) {
    const int t = threadIdx.x;
    int4* p = (int4*)aux;
    int4 q0 = p[4 * t], q1 = p[4 * t + 1], q2 = p[4 * t + 2], q3 = p[4 * t + 3];
    int v[16] = {q0.x, q0.y, q0.z, q0.w, q1.x, q1.y, q1.z, q1.w,
                 q2.x, q2.y, q2.z, q2.w, q3.x, q3.y, q3.z, q3.w};
    int pre[16];
    int run = 0;
    #pragma unroll
    for (int i = 0; i < 16; ++i) { pre[i] = run; run += v[i]; }
    int ws = run;
    #pragma unroll
    for (int off = 1; off < 64; off <<= 1) {
        int o = __shfl_up(ws, off);
        if (t >= off) ws += o;
    }
    int excl = ws - run;
    #pragma unroll
    for (int i = 0; i < 16; ++i) v[i] = excl + pre[i];
    q0 = make_int4(v[0], v[1], v[2], v[3]);
    q1 = make_int4(v[4], v[5], v[6], v[7]);
    q2 = make_int4(v[8], v[9], v[10], v[11]);
    q3 = make_int4(v[12], v[13], v[14], v[15]);
    p[4 * t] = q0; p[4 * t + 1] = q1; p[4 * t + 2] = q2; p[4 * t + 3] = q3;
}

__global__ __launch_bounds__(256) void gin_scan_c(int* __restrict__ cnt,
                                                  const int* __restrict__ aux) {
    const int t = threadIdx.x, blk = blockIdx.x;
    int base = aux[blk];
    int4* p = (int4*)(cnt + blk * 1024);
    int4 vv = p[t];
    vv.x += base; vv.y += base; vv.z += base; vv.w += base;
    p[t] = vv;
}

// ---------------- scatter: LDS-staged, FLAT flush (binary-search key) -------
__global__ __launch_bounds__(HSB) void gin_scatter(const int* __restrict__ ei,
                                                   const int* __restrict__ cnt,
                                                   unsigned int* __restrict__ packed) {
    __shared__ int cur[NKEYS];            // 16 KB (startl, then bumped to endl)
    __shared__ int dif[NKEYS];            // 16 KB (gbase - startl)
    __shared__ unsigned int E[CHUNK];     // 122.1 KB
    __shared__ int wtot[16];
    const int t = threadIdx.x, s = blockIdx.x;
    const int lane = t & 63, wave = t >> 6;

    // local exclusive scan of this block's per-key counts via flat-scan diffs
    const int kb = 4 * t;
    int a0, a1, a2, a3, c0, c1, c2, c3;
    {
        int f0 = (kb + 0) * NSCAT + s;
        int f1 = (kb + 1) * NSCAT + s;
        int f2 = (kb + 2) * NSCAT + s;
        int f3 = (kb + 3) * NSCAT + s;
        a0 = cnt[f0]; a1 = cnt[f1]; a2 = cnt[f2]; a3 = cnt[f3];
        c0 = cnt[f0 + 1] - a0;
        c1 = cnt[f1 + 1] - a1;
        c2 = cnt[f2 + 1] - a2;
        int n3 = (f3 + 1 < SCAN_N) ? cnt[f3 + 1] : N_EDGES;
        c3 = n3 - a3;
    }
    int sum4 = c0 + c1 + c2 + c3;
    int ws = sum4;
    #pragma unroll
    for (int off = 1; off < 64; off <<= 1) {
        int o = __shfl_up(ws, off);
        if (lane >= off) ws += o;
    }
    if (lane == 63) wtot[wave] = ws;
    __syncthreads();
    int wbase = 0;
    for (int i = 0; i < wave; ++i) wbase += wtot[i];
    int excl = wbase + ws - sum4;
    int s0 = excl, s1 = excl + c0, s2 = excl + c0 + c1, s3 = excl + c0 + c1 + c2;
    cur[kb + 0] = s0;  dif[kb + 0] = a0 - s0;
    cur[kb + 1] = s1;  dif[kb + 1] = a1 - s1;
    cur[kb + 2] = s2;  dif[kb + 2] = a2 - s2;
    cur[kb + 3] = s3;  dif[kb + 3] = a3 - s3;
    __syncthreads();

    // phase 1: place edges into LDS at locally-sorted positions
    const int* src = ei;
    const int* dst = ei + N_EDGES;
    const int e0 = s * CHUNK, e1 = e0 + CHUNK;
    for (int e = e0 + t; e < e1; e += HSB) {
        int d = dst[e];
        int key = d >> 7;
        int lofs = atomicAdd(&cur[key], 1);
        E[lofs] = (unsigned int)src[e] | ((unsigned int)(d & (TILE - 1)) << 19);
    }
    __syncthreads();
    // post-phase1: cur[k] = local END of key k's run (monotone, cur[last]=CHUNK)

    // phase 2: flat flush, one store per element, all lanes active
    for (int i = t; i < CHUNK; i += HSB) {
        unsigned int e = E[i];
        int lo = 0, hi = NKEYS;
        #pragma unroll
        for (int it = 0; it < 13; ++it) {      // ceil(log2(NKEYS+1)) = 13
            int mid = (lo + hi) >> 1;
            if (cur[mid] > i) hi = mid; else lo = mid + 1;
        }
        packed[dif[lo] + i] = e;
    }
}

// ---------------- winsort: reorder each bucket's edges by src window --------
__global__ __launch_bounds__(256) void gin_winsort(unsigned int* __restrict__ packed,
                                                   const int* __restrict__ cnt) {
    __shared__ unsigned int E[CAP];
    __shared__ unsigned int F[CAP];
    __shared__ int cw[NW * 256];
    __shared__ int winBase[NW];
    __shared__ int wt[NW];
    const int t = threadIdx.x, bucket = blockIdx.x;
    const int beg = cnt[bucket * NSCAT];
    const int end = cnt[(bucket + 1) * NSCAT];
    const int n = end - beg;
    if (n > CAP) return;                      // identity fallback (rare/never)

    for (int i = t; i < n; i += 256) E[i] = packed[beg + i];
    __syncthreads();

    int c[NW];
    #pragma unroll
    for (int w = 0; w < NW; ++w) c[w] = 0;
    for (int i = t; i < n; i += 256) { int w = (E[i] & 0x7FFFFu) >> 16; c[w]++; }
    #pragma unroll
    for (int w = 0; w < NW; ++w) cw[w * 256 + t] = c[w];
    __syncthreads();

    const int lane = t & 63, wv = t >> 6;
    for (int rep = 0; rep < 2; ++rep) {
        int w = wv + rep * 4;
        int carry = 0;
        #pragma unroll
        for (int chunkk = 0; chunkk < 4; ++chunkk) {
            int idx = chunkk * 64 + lane;
            int val = cw[w * 256 + idx];
            int sc = val;
            #pragma unroll
            for (int off = 1; off < 64; off <<= 1) {
                int o = __shfl_up(sc, off);
                if (lane >= off) sc += o;
            }
            cw[w * 256 + idx] = sc - val + carry;
            carry += __shfl(sc, 63);
        }
        if (lane == 0) wt[w] = carry;
    }
    __syncthreads();
    if (t == 0) {
        int run = 0;
        #pragma unroll
        for (int w = 0; w < NW; ++w) { winBase[w] = run; run += wt[w]; }
    }
    __syncthreads();

    int runc[NW];
    #pragma unroll
    for (int w = 0; w < NW; ++w) runc[w] = 0;
    for (int i = t; i < n; i += 256) {
        unsigned int pk = E[i];
        int w = (pk & 0x7FFFFu) >> 16;
        int pos = winBase[w] + cw[w * 256 + t] + runc[w]++;
        F[pos] = pk;
    }
    __syncthreads();
    for (int i = t; i < n; i += 256) packed[beg + i] = F[i];
}

// ---------------- reduce: 2 waves/bucket (interleaved groups), merged -------
__global__ __launch_bounds__(RB) void gin_reduce(
    const unsigned int* __restrict__ packed,
    const int* __restrict__ cnt,
    const float* __restrict__ xa,
    const float* __restrict__ xb,
    const int* __restrict__ batch,
    const float* __restrict__ w1,
    const float* __restrict__ b1,
    const float* __restrict__ v,
    const float* __restrict__ c,
    float* __restrict__ out)
{
    __shared__ float tile[WPB * TILE * TSR];   // 24 KB: one 6 KB slice per wave
    __shared__ float w1s[IN_DIM * HID];
    __shared__ float b1s[HID];
    __shared__ float vs[HID];
    __shared__ float cs;

    const int t = threadIdx.x;
    const int wave = t >> 6, lane = t & 63;

    for (int i = t; i < WPB * TILE * TSR; i += RB) tile[i] = 0.f;
    for (int i = t; i < IN_DIM * HID; i += RB) w1s[i] = w1[i];
    if (t < HID) { b1s[t] = b1[t]; vs[t] = v[t]; }
    if (t == 0) cs = *c;
    __syncthreads();

    const int pair = wave >> 1;                 // which bucket in block
    const int half = wave & 1;                  // which group parity
    const int bucket = blockIdx.x * 2 + pair;
    float* tw = tile + wave * (TILE * TSR);     // wave-private slice

    const int beg = cnt[bucket * NSCAT];
    const int end = cnt[(bucket + 1) * NSCAT];  // padded keys hold N_EDGES

    // INTERLEAVED split: wave `half` takes alternating 64-edge groups.
    // Both waves (and all blocks) march through src windows in lockstep,
    // keeping the active gather footprint cache-resident (round-0 locality,
    // round-3 parallelism). Contiguous halves cost 3.2x HBM fetch (measured).
    for (int p0 = beg + half * 64; p0 < end; p0 += 128) {
        int p = p0 + lane;
        bool valid = p < end;
        unsigned int pk = valid ? packed[p] : 0u;
        int local = (int)(pk >> 19);             // 0..127
        int src = (int)(pk & 0x7FFFFu);
        const float4* xr = (const float4*)(xa + (size_t)src * 8);
        float4 a0 = xr[0], a1 = xr[1];
        float a2 = xb[src];

        // one-shot match mask + rank; conflict rounds cost 1 ballot each
        unsigned long long act0 = __ballot(valid);
        unsigned long long m = act0;
        #pragma unroll
        for (int bq = 0; bq < 7; ++bq) {
            unsigned long long bal = __ballot((local >> bq) & 1);
            m &= ((local >> bq) & 1) ? bal : ~bal;
        }
        unsigned long long mybit = 1ULL << lane;
        int rank = __popcll(m & (mybit - 1ULL));
        bool pending = valid;
        int r = 0;
        while (__any(pending)) {
            bool lead = pending && (rank == r);
            if (lead) {
                float4* row = (float4*)(tw + local * TSR);
                float4 r0 = row[0], r1 = row[1];
                float r2 = tw[local * TSR + 8];
                r0.x += a0.x; r0.y += a0.y; r0.z += a0.z; r0.w += a0.w;
                r1.x += a1.x; r1.y += a1.y; r1.z += a1.z; r1.w += a1.w;
                row[0] = r0; row[1] = r1;
                tw[local * TSR + 8] = r2 + a2;
                pending = false;
            }
            ++r;
        }
    }
    __syncthreads();

    // merge odd wave slice into even (per bucket), all 256 threads cooperate
    {
        float4* t4 = (float4*)tile;
        const int SL4 = TILE * TSR / 4;        // 384 float4 per slice
        for (int i = t; i < 2 * SL4; i += RB) {
            int pp = i / SL4, j = i - pp * SL4;
            float4 A = t4[(2 * pp) * SL4 + j];
            float4 B = t4[(2 * pp + 1) * SL4 + j];
            A.x += B.x; A.y += B.y; A.z += B.z; A.w += B.w;
            t4[(2 * pp) * SL4 + j] = A;
        }
    }
    __syncthreads();

    // fused MLP + scalar collapse + segmented pooled reduction
    const float* tb = tile + (2 * pair) * (TILE * TSR);
    const int nloc = half * 64 + lane;
    const int node = bucket * TILE + nloc;
    float s = 0.f;
    int b = -1;
    if (node < N_NODES) {
        const float4* xr = (const float4*)(xa + (size_t)node * 8);
        float4 q0 = xr[0], q1 = xr[1];
        float tv[IN_DIM];
        tv[0] = q0.x + tb[nloc * TSR + 0];
        tv[1] = q0.y + tb[nloc * TSR + 1];
        tv[2] = q0.z + tb[nloc * TSR + 2];
        tv[3] = q0.w + tb[nloc * TSR + 3];
        tv[4] = q1.x + tb[nloc * TSR + 4];
        tv[5] = q1.y + tb[nloc * TSR + 5];
        tv[6] = q1.z + tb[nloc * TSR + 6];
        tv[7] = q1.w + tb[nloc * TSR + 7];
        tv[8] = xb[node] + tb[nloc * TSR + 8];
        s = cs;
        #pragma unroll
        for (int j = 0; j < HID; ++j) {
            float z = b1s[j];
            #pragma unroll
            for (int k = 0; k < IN_DIM; ++k)
                z = fmaf(tv[k], w1s[k * HID + j], z);
            s += fmaxf(z, 0.f) * vs[j];
        }
        b = batch[node];
    }
    #pragma unroll
    for (int off = 1; off < 64; off <<= 1) {
        float so = __shfl_up(s, off);
        int bo = __shfl_up(b, off);
        if (lane >= off && bo == b) s += so;
    }
    int nb = __shfl_down(b, 1);
    bool tail = (lane == 63) || (nb != b);
    if (tail && b >= 0) atomicAdd(&out[b], s);
}

extern "C" void kernel_launch(void* const* d_in, const int* in_sizes, int n_in,
                              void* d_out, int out_size, void* d_ws, size_t ws_size,
                              hipStream_t stream) {
    const float* x     = (const float*)d_in[0];
    const int*   ei    = (const int*)d_in[1];
    const int*   batch = (const int*)d_in[2];
    const float* w1    = (const float*)d_in[3];
    const float* b1    = (const float*)d_in[4];
    const float* w2    = (const float*)d_in[5];
    const float* b2    = (const float*)d_in[6];
    const float* w3    = (const float*)d_in[7];
    const float* b3    = (const float*)d_in[8];
    float* out = (float*)d_out;

    // workspace (~54.2 MB)
    float* xa = (float*)d_ws;                                           // 16 MB
    float* xb = xa + (size_t)N_NODES * 8;                               // 2 MB
    unsigned int* packed = (unsigned int*)(xb + N_NODES);               // 32 MB
    int* cnt = (int*)(packed + N_EDGES);                                // 4 MB
    int* aux = cnt + SCAN_N;                                            // 4 KB
    float* v = (float*)(aux + SCAN_BLOCKS);                             // 64 floats
    float* c = v + HID;                                                 // 1 float

    gin_xpad<<<(N_NODES * IN_DIM + 255) / 256, 256, 0, stream>>>(x, xa, xb);
    gin_precompute<<<(N_GRAPHS + 255) / 256, 256, 0, stream>>>(w2, b2, w3, b3, out, v, c);
    gin_hist<<<NSCAT, HSB, 0, stream>>>(ei, cnt);
    gin_scan_a<<<SCAN_BLOCKS, 256, 0, stream>>>(cnt, aux);
    gin_scan_b<<<1, 64, 0, stream>>>(aux);
    gin_scan_c<<<SCAN_BLOCKS, 256, 0, stream>>>(cnt, aux);
    gin_scatter<<<NSCAT, HSB, 0, stream>>>(ei, cnt, packed);
    gin_winsort<<<NKEYS_USED, 256, 0, stream>>>(packed, cnt);
    gin_reduce<<<RGRID, RB, 0, stream>>>(packed, cnt, xa, xb, batch, w1, b1, v, c, out);
}